// Round 1
// 885.575 us; speedup vs baseline: 1.3357x; 1.3357x over previous
//
#include <hip/hip_runtime.h>
#include <math.h>

// Router: logits = x[32768,4096] @ w[64,4096]^T, softmax->top2->renorm.
//
// MFMA version: fp32 inputs split into bf16 hi+lo (x=xh+xl, w=wh+wl, truncation),
// logits = xh*wh + xl*wh + xh*wl via mfma_f32_16x16x32_bf16 (error ~3e-5 << DELTA).
//
// d_out layout (float32):
//   [0      , 65536 ) : indices [8,4096,2] as float
//   [65536  , 131072) : weights [8,4096,2]
//   [131072 , end   ) : logits  [8,4096,64]
//
// d_ws layout:
//   [0      , 128K  ) : flags   (int per row)
//   [128K   , 128K+1M): w split bf16: hi plane [64][4096] ushort, then lo plane
//
// pass2 (unchanged): fp64 recompute of flagged (ambiguous) rows for exactness.

#define DELTA  1e-3f
#define LS     68            // logits LDS stride (floats)
#define WPLANE 262144        // elems per w bf16 plane (64*4096)

typedef __bf16 bf16x8 __attribute__((ext_vector_type(8)));
typedef float  f32x4  __attribute__((ext_vector_type(4)));

#define MFMA(a, b, c) __builtin_amdgcn_mfma_f32_16x16x32_bf16(a, b, c, 0, 0, 0)

__device__ __forceinline__ void split1(float x, unsigned short& h, unsigned short& l)
{
    const unsigned xb = __float_as_uint(x);
    const unsigned hb = xb & 0xffff0000u;
    h = (unsigned short)(hb >> 16);
    const float fl = x - __uint_as_float(hb);      // exact in fp32
    l = (unsigned short)(__float_as_uint(fl) >> 16);
}

// ---- w pre-split: fp32 [64][4096] -> bf16 hi/lo planes in workspace ----
__global__ __launch_bounds__(256)
void router_wconv(const float* __restrict__ w, unsigned short* __restrict__ wsp)
{
    const int i = (blockIdx.x * 256 + threadIdx.x) * 4;   // 256 blocks cover 262144
    const float4 v = *(const float4*)(w + i);
    ushort4 h4, l4;
    split1(v.x, h4.x, l4.x);
    split1(v.y, h4.y, l4.y);
    split1(v.z, h4.z, l4.z);
    split1(v.w, h4.w, l4.w);
    *(ushort4*)(wsp + i)          = h4;
    *(ushort4*)(wsp + WPLANE + i) = l4;
}

// ---- pass1: MFMA GEMM + logits + top-2 + ambiguity flags ----
// BM=32 rows/block, 128 threads (2 waves x 16 rows), KT=128, grid 1024.
__global__ __launch_bounds__(128, 2)
void router_pass1(const float* __restrict__ x,
                  const unsigned short* __restrict__ wsp,
                  float* __restrict__ out,
                  int* __restrict__ flags)
{
    __shared__ unsigned short a_hi[32 * 128];   // 8 KB, XOR-swizzled
    __shared__ unsigned short a_lo[32 * 128];   // 8 KB
    __shared__ float l_lds[32 * LS];            // 8.5 KB

    const int tid  = threadIdx.x;
    const int lane = tid & 63;
    const int wv   = tid >> 6;                  // 0..1
    const int row0 = blockIdx.x * 32;

    const int fr = lane & 15;                   // frag row (A) / col (B,D)
    const int fk = (lane >> 4) << 3;            // frag k offset: 0,8,16,24

    f32x4 acc[4];
#pragma unroll
    for (int ct = 0; ct < 4; ++ct) {
        acc[ct][0] = 0.f; acc[ct][1] = 0.f; acc[ct][2] = 0.f; acc[ct][3] = 0.f;
    }

    // A fragment LDS addressing (row stride 256B, XOR swizzle on byte offset)
    const int arow = wv * 16 + fr;
    const unsigned asw = (unsigned)((arow & 7) << 4);
    const char* ahbase = (const char*)a_hi + arow * 256;
    const char* albase = (const char*)a_lo + arow * 256;

    // B fragment global bases: lane reads w[e=ct*16+fr][k0+fk .. +7] (16B contig)
    const unsigned short* wb[4];
#pragma unroll
    for (int ct = 0; ct < 4; ++ct)
        wb[ct] = wsp + (size_t)(ct * 16 + fr) * 4096 + fk;

    // prologue: reg-stage tile 0
    float4 xv[8];
#pragma unroll
    for (int j = 0; j < 8; ++j) {
        const int f = j * 512 + tid * 4;
        const int r = f >> 7, k = f & 127;
        xv[j] = *(const float4*)(x + (size_t)(row0 + r) * 4096 + k);
    }

    for (int t = 0; t < 32; ++t) {
        __syncthreads();                        // LDS readers of tile t-1 done
        // convert + swizzled LDS write
#pragma unroll
        for (int j = 0; j < 8; ++j) {
            const int f = j * 512 + tid * 4;
            const int r = f >> 7, k = f & 127;
            const float4 v = xv[j];
            ushort4 h4, l4;
            split1(v.x, h4.x, l4.x);
            split1(v.y, h4.y, l4.y);
            split1(v.z, h4.z, l4.z);
            split1(v.w, h4.w, l4.w);
            const unsigned off = (unsigned)(r * 256) +
                                 (((unsigned)(k * 2)) ^ ((unsigned)((r & 7) << 4)));
            *(ushort4*)((char*)a_hi + off) = h4;
            *(ushort4*)((char*)a_lo + off) = l4;
        }
        __syncthreads();                        // tile t ready

        // issue next tile's global loads now (in flight across MFMA phase)
        if (t < 31) {
            const int k0n = (t + 1) * 128;
#pragma unroll
            for (int j = 0; j < 8; ++j) {
                const int f = j * 512 + tid * 4;
                const int r = f >> 7, k = f & 127;
                xv[j] = *(const float4*)(x + (size_t)(row0 + r) * 4096 + k0n + k);
            }
        }

        // 4 k-steps of K=32; 3 split-term MFMAs per col-tile
#pragma unroll
        for (int ks = 0; ks < 4; ++ks) {
            const unsigned kk = (unsigned)(ks * 32 + fk);
            const bf16x8 ah = *(const bf16x8*)(ahbase + ((kk * 2) ^ asw));
            const bf16x8 al = *(const bf16x8*)(albase + ((kk * 2) ^ asw));
#pragma unroll
            for (int ct = 0; ct < 4; ++ct) {
                const unsigned short* p = wb[ct] + (size_t)(t * 128 + ks * 32);
                const bf16x8 bh = *(const bf16x8*)(p);
                const bf16x8 bl = *(const bf16x8*)(p + WPLANE);
                acc[ct] = MFMA(ah, bh, acc[ct]);
                acc[ct] = MFMA(al, bh, acc[ct]);
                acc[ct] = MFMA(ah, bl, acc[ct]);
            }
        }
    }

    // D layout: col = lane&15, row = (lane>>4)*4 + reg  [m89-verified]
#pragma unroll
    for (int ct = 0; ct < 4; ++ct) {
#pragma unroll
        for (int i = 0; i < 4; ++i) {
            l_lds[(wv * 16 + (lane >> 4) * 4 + i) * LS + ct * 16 + fr] = acc[ct][i];
        }
    }
    __syncthreads();

    // logits -> global
    {
        float* lg = out + 131072 + (size_t)row0 * 64;
#pragma unroll
        for (int j = 0; j < 4; ++j) {
            const int f = j * 512 + tid * 4;
            const int r = f >> 6, e = f & 63;
            const float4 v = *(const float4*)(&l_lds[r * LS + e]);
            *(float4*)(lg + f) = v;
        }
    }

    // top-2 + renorm + ambiguity flag (one thread per row)
    if (tid < 32) {
        const int r = tid;
        float b1 = -3.4e38f, b2 = -3.4e38f, b3 = -3.4e38f;
        int i1 = 0, i2 = 0;
        for (int eq = 0; eq < 16; ++eq) {
            const float4 v4 = *(const float4*)(&l_lds[r * LS + eq * 4]);
            const float vv[4] = {v4.x, v4.y, v4.z, v4.w};
#pragma unroll
            for (int j = 0; j < 4; ++j) {
                const float v = vv[j];
                const int   e = eq * 4 + j;
                if (v > b1)      { b3 = b2; b2 = b1; i2 = i1; b1 = v; i1 = e; }
                else if (v > b2) { b3 = b2; b2 = v; i2 = e; }
                else if (v > b3) { b3 = v; }
            }
        }
        const float g   = __expf(b2 - b1);
        const float inv = 1.0f / (1.0f + g);
        const size_t o  = (size_t)(row0 + r) * 2;
        out[o]     = (float)i1;
        out[o + 1] = (float)i2;
        out[65536 + o]     = inv;
        out[65536 + o + 1] = g * inv;
        flags[row0 + r] = ((b1 - b2 < DELTA) || (b2 - b3 < DELTA)) ? 1 : 0;
    }
}

// ---- pass2: fp64 repair of flagged rows (unchanged) ----
__global__ __launch_bounds__(256, 2)
void router_pass2(const float* __restrict__ x,
                  const float* __restrict__ w,
                  float* __restrict__ out,
                  const int* __restrict__ flags)
{
    const int wv   = threadIdx.x >> 6;
    const int lane = threadIdx.x & 63;
    const int base = blockIdx.x * 64 + wv * 16;

    for (int r = 0; r < 16; ++r) {
        const int row = base + r;
        if (!flags[row]) continue;   // wave-uniform

        const float* lg = out + 131072 + (size_t)row * 64;
        const float my = lg[lane];
        float wval = my;

        int ec[4];
#pragma unroll
        for (int m = 0; m < 4; ++m) {
            float v = wval;
            int   id = lane;
            for (int off = 32; off; off >>= 1) {
                const float ov = __shfl_xor(v, off);
                const int   oi = __shfl_xor(id, off);
                if (ov > v || (ov == v && oi < id)) { v = ov; id = oi; }
            }
            ec[m] = id;
            if (lane == id) wval = -3.4e38f;
        }

        double s0 = 0.0, s1 = 0.0, s2 = 0.0, s3 = 0.0;
        const float* xr = x + (size_t)row * 4096;
        const float* w0 = w + (size_t)ec[0] * 4096;
        const float* w1 = w + (size_t)ec[1] * 4096;
        const float* w2 = w + (size_t)ec[2] * 4096;
        const float* w3 = w + (size_t)ec[3] * 4096;
        for (int k = lane; k < 4096; k += 64) {
            const double xd = (double)xr[k];
            s0 += xd * (double)w0[k];
            s1 += xd * (double)w1[k];
            s2 += xd * (double)w2[k];
            s3 += xd * (double)w3[k];
        }
        for (int off = 32; off; off >>= 1) {
            s0 += __shfl_xor(s0, off);
            s1 += __shfl_xor(s1, off);
            s2 += __shfl_xor(s2, off);
            s3 += __shfl_xor(s3, off);
        }

        if (lane == 0) {
            double v4[4] = { s0, s1, s2, s3 };
            int    id[4] = { ec[0], ec[1], ec[2], ec[3] };
#pragma unroll
            for (int a = 0; a < 3; ++a)
#pragma unroll
                for (int b = a + 1; b < 4; ++b)
                    if (v4[b] > v4[a] || (v4[b] == v4[a] && id[b] < id[a])) {
                        double tv = v4[a]; v4[a] = v4[b]; v4[b] = tv;
                        int    ti = id[a]; id[a] = id[b]; id[b] = ti;
                    }
            const double g   = exp(v4[1] - v4[0]);
            const double inv = 1.0 / (1.0 + g);
            const size_t o   = (size_t)row * 2;
            out[o]     = (float)id[0];
            out[o + 1] = (float)id[1];
            out[65536 + o]     = (float)inv;
            out[65536 + o + 1] = (float)(g * inv);
        }
    }
}

extern "C" void kernel_launch(void* const* d_in, const int* in_sizes, int n_in,
                              void* d_out, int out_size, void* d_ws, size_t ws_size,
                              hipStream_t stream) {
    const float* x = (const float*)d_in[0];   // [8,4096,4096]
    const float* w = (const float*)d_in[1];   // [64,4096]
    float* out = (float*)d_out;
    int* flags = (int*)d_ws;                                        // 128 KB
    unsigned short* wsp = (unsigned short*)((char*)d_ws + 131072);  // 1 MB hi+lo

    hipLaunchKernelGGL(router_wconv, dim3(256),  dim3(256), 0, stream, w, wsp);
    hipLaunchKernelGGL(router_pass1, dim3(1024), dim3(128), 0, stream, x, wsp, out, flags);
    hipLaunchKernelGGL(router_pass2, dim3(512),  dim3(256), 0, stream, x, w, out, flags);
}

// Round 2
// 874.401 us; speedup vs baseline: 1.3528x; 1.0128x over previous
//
#include <hip/hip_runtime.h>
#include <math.h>

// Router: logits = x[32768,4096] @ w[64,4096]^T, softmax->top2->renorm.
//
// MFMA version: fp32 inputs split into bf16 hi+lo (x=xh+xl, w=wh+wl, truncation),
// logits = xh*wh + xl*wh + xh*wl via mfma_f32_16x16x32_bf16 (error ~1e-5 << DELTA).
//
// pass1 v2: barrier-free K-loop.
//   - x staged fp32 via global_load_lds (16B), double-buffered 2x32KB.
//   - global SOURCE pre-swizzled (XOR (row&7)<<4) so linear LDS dest + swizzled
//     ds_read_b128 is bank-conflict-free (rule: both-sides-or-neither).
//   - each wave stages exactly the 16 rows it consumes -> LDS deps wave-private
//     -> no __syncthreads in the K loop; counted s_waitcnt vmcnt(8) keeps the
//     next tile's 8 loads in flight across the whole MFMA phase (never drain 0).
//   - hi/lo bf16 split done in-register per fragment (no ushort LDS planes).
//
// d_out layout (float32):
//   [0      , 65536 ) : indices [8,4096,2] as float
//   [65536  , 131072) : weights [8,4096,2]
//   [131072 , end   ) : logits  [8,4096,64]
//
// d_ws layout:
//   [0      , 128K  ) : flags   (int per row)
//   [128K   , 128K+1M): w split bf16: hi plane [64][4096] ushort, then lo plane
//
// pass2 (unchanged): fp64 recompute of flagged (ambiguous) rows for exactness.

#define DELTA  1e-3f
#define LS     68            // logits LDS stride (floats)
#define WPLANE 262144        // elems per w bf16 plane (64*4096)
#define NT     32            // K tiles (4096 / 128)

typedef __bf16 bf16x8 __attribute__((ext_vector_type(8)));
typedef float  f32x4  __attribute__((ext_vector_type(4)));

#define MFMA(a, b, c) __builtin_amdgcn_mfma_f32_16x16x32_bf16(a, b, c, 0, 0, 0)

#define GLL16(gp, lp) __builtin_amdgcn_global_load_lds(                          \
    (const __attribute__((address_space(1))) unsigned*)(gp),                     \
    (__attribute__((address_space(3))) unsigned*)(lp), 16, 0, 0)

__device__ __forceinline__ void split1(float x, unsigned short& h, unsigned short& l)
{
    const unsigned xb = __float_as_uint(x);
    const unsigned hb = xb & 0xffff0000u;
    h = (unsigned short)(hb >> 16);
    const float fl = x - __uint_as_float(hb);      // exact in fp32
    l = (unsigned short)(__float_as_uint(fl) >> 16);
}

// 8 fp32 -> bf16 hi plane + bf16 lo plane (truncation; identical to split1)
__device__ __forceinline__ void split8(const f32x4 v0, const f32x4 v1,
                                       bf16x8& ah, bf16x8& al)
{
    union U { bf16x8 v; unsigned u[4]; };
    U h, l;
    const unsigned a0 = __float_as_uint(v0[0]), a1 = __float_as_uint(v0[1]);
    const unsigned a2 = __float_as_uint(v0[2]), a3 = __float_as_uint(v0[3]);
    const unsigned b0 = __float_as_uint(v1[0]), b1 = __float_as_uint(v1[1]);
    const unsigned b2 = __float_as_uint(v1[2]), b3 = __float_as_uint(v1[3]);
    h.u[0] = (a0 >> 16) | (a1 & 0xffff0000u);
    h.u[1] = (a2 >> 16) | (a3 & 0xffff0000u);
    h.u[2] = (b0 >> 16) | (b1 & 0xffff0000u);
    h.u[3] = (b2 >> 16) | (b3 & 0xffff0000u);
    const float f0 = v0[0] - __uint_as_float(a0 & 0xffff0000u);
    const float f1 = v0[1] - __uint_as_float(a1 & 0xffff0000u);
    const float f2 = v0[2] - __uint_as_float(a2 & 0xffff0000u);
    const float f3 = v0[3] - __uint_as_float(a3 & 0xffff0000u);
    const float f4 = v1[0] - __uint_as_float(b0 & 0xffff0000u);
    const float f5 = v1[1] - __uint_as_float(b1 & 0xffff0000u);
    const float f6 = v1[2] - __uint_as_float(b2 & 0xffff0000u);
    const float f7 = v1[3] - __uint_as_float(b3 & 0xffff0000u);
    l.u[0] = (__float_as_uint(f0) >> 16) | (__float_as_uint(f1) & 0xffff0000u);
    l.u[1] = (__float_as_uint(f2) >> 16) | (__float_as_uint(f3) & 0xffff0000u);
    l.u[2] = (__float_as_uint(f4) >> 16) | (__float_as_uint(f5) & 0xffff0000u);
    l.u[3] = (__float_as_uint(f6) >> 16) | (__float_as_uint(f7) & 0xffff0000u);
    ah = h.v;
    al = l.v;
}

// ---- w pre-split: fp32 [64][4096] -> bf16 hi/lo planes in workspace ----
__global__ __launch_bounds__(256)
void router_wconv(const float* __restrict__ w, unsigned short* __restrict__ wsp)
{
    const int i = (blockIdx.x * 256 + threadIdx.x) * 4;   // 256 blocks cover 262144
    const float4 v = *(const float4*)(w + i);
    ushort4 h4, l4;
    split1(v.x, h4.x, l4.x);
    split1(v.y, h4.y, l4.y);
    split1(v.z, h4.z, l4.z);
    split1(v.w, h4.w, l4.w);
    *(ushort4*)(wsp + i)          = h4;
    *(ushort4*)(wsp + WPLANE + i) = l4;
}

// ---- pass1: MFMA GEMM + logits + top-2 + ambiguity flags ----
// BM=64 rows/block, 256 threads (4 waves x 16 rows each), KT=128, grid 512.
__global__ __launch_bounds__(256, 2)
void router_pass1(const float* __restrict__ x,
                  const unsigned short* __restrict__ wsp,
                  float* __restrict__ out,
                  int* __restrict__ flags)
{
    // two fp32 A-tile buffers [64 rows][512B], epilogue overlays logits here
    __shared__ __align__(16) char smem[65536];

    const int tid  = threadIdx.x;
    const int lane = tid & 63;
    const int wv   = tid >> 6;                  // 0..3
    const int row0 = blockIdx.x * 64;

    const int fr = lane & 15;                   // frag row (A) / col (B,D)
    const int fq = lane >> 4;                   // 0..3; k offset = fq*8

    f32x4 acc[4];
#pragma unroll
    for (int ct = 0; ct < 4; ++ct) {
        acc[ct][0] = 0.f; acc[ct][1] = 0.f; acc[ct][2] = 0.f; acc[ct][3] = 0.f;
    }

    // ---- staging addresses (loop-invariant; only tile offset varies) ----
    // subtile s = wv*8+j covers rows 2s,2s+1 -> wave wv stages rows wv*16..+15,
    // exactly the rows it consumes (wave-private LDS).
    const int half  = lane >> 5;                 // 0/1: which row of the subtile
    const unsigned colb = (unsigned)((lane & 31) * 16);
    const char* gsrc[8];
    char*       lbas[8];
#pragma unroll
    for (int j = 0; j < 8; ++j) {
        const int row = wv * 16 + 2 * j + half;
        const unsigned swz = colb ^ ((unsigned)(row & 7) << 4);  // pre-swizzled source
        gsrc[j] = (const char*)x + (size_t)(row0 + row) * 16384 + swz;
        lbas[j] = smem + (wv * 8 + j) * 1024;                    // linear LDS dest
    }

    // B fragment global bases: lane reads w[e=ct*16+fr][k0+fq*8 .. +7] (16B, L2)
    const unsigned short* wb[4];
#pragma unroll
    for (int ct = 0; ct < 4; ++ct)
        wb[ct] = wsp + (size_t)(ct * 16 + fr) * 4096 + fq * 8;

    // A fragment read base (swizzled ds_read_b128)
    const int arow = wv * 16 + fr;
    const unsigned aswz = (unsigned)((arow & 7) << 4);
    const char* abase = smem + arow * 512;

    // prologue: issue tile 0 into buf 0
#pragma unroll
    for (int j = 0; j < 8; ++j) GLL16(gsrc[j], lbas[j]);

#pragma unroll 1
    for (int t = 0; t < NT; ++t) {
        if (t + 1 < NT) {
            const size_t go = (size_t)(t + 1) * 512;
            const int    bo = ((t + 1) & 1) * 32768;
#pragma unroll
            for (int j = 0; j < 8; ++j) GLL16(gsrc[j] + go, lbas[j] + bo);
            // tile t's 8 loads complete; tile t+1's 8 stay in flight
            asm volatile("s_waitcnt vmcnt(8)" ::: "memory");
        } else {
            asm volatile("s_waitcnt vmcnt(0)" ::: "memory");
        }
        __builtin_amdgcn_sched_barrier(0);

        const char* bufc = abase + (t & 1) * 32768;
#pragma unroll
        for (int ks = 0; ks < 4; ++ks) {
            const unsigned i0 = (unsigned)(ks * 128 + fq * 32);
            const f32x4 v0 = *(const f32x4*)(bufc + ( i0        ^ aswz));
            const f32x4 v1 = *(const f32x4*)(bufc + ((i0 + 16u) ^ aswz));
            bf16x8 ah, al;
            split8(v0, v1, ah, al);
#pragma unroll
            for (int ct = 0; ct < 4; ++ct) {
                const unsigned short* p = wb[ct] + t * 128 + ks * 32;
                const bf16x8 bh = *(const bf16x8*)(p);
                const bf16x8 bl = *(const bf16x8*)(p + WPLANE);
                acc[ct] = MFMA(ah, bh, acc[ct]);
                acc[ct] = MFMA(al, bh, acc[ct]);
                acc[ct] = MFMA(ah, bl, acc[ct]);
            }
        }
    }

    // ---- epilogue: logits via LDS (overlay A buffers), top-2, flags ----
    __syncthreads();                            // all waves done with A buffers
    float* l_lds = (float*)smem;
    // D layout: col = lane&15, row = (lane>>4)*4 + reg  [m89-verified]
#pragma unroll
    for (int ct = 0; ct < 4; ++ct) {
#pragma unroll
        for (int i = 0; i < 4; ++i) {
            l_lds[(wv * 16 + fq * 4 + i) * LS + ct * 16 + fr] = acc[ct][i];
        }
    }
    __syncthreads();

    {
        float* lg = out + 131072 + (size_t)row0 * 64;
#pragma unroll
        for (int j = 0; j < 4; ++j) {
            const int f = j * 1024 + tid * 4;
            const int r = f >> 6, e = f & 63;
            const float4 v = *(const float4*)(&l_lds[r * LS + e]);
            *(float4*)(lg + f) = v;
        }
    }

    if (tid < 64) {
        const int r = tid;
        float b1 = -3.4e38f, b2 = -3.4e38f, b3 = -3.4e38f;
        int i1 = 0, i2 = 0;
        for (int eq = 0; eq < 16; ++eq) {
            const float4 v4 = *(const float4*)(&l_lds[r * LS + eq * 4]);
            const float vv[4] = {v4.x, v4.y, v4.z, v4.w};
#pragma unroll
            for (int j = 0; j < 4; ++j) {
                const float v = vv[j];
                const int   e = eq * 4 + j;
                if (v > b1)      { b3 = b2; b2 = b1; i2 = i1; b1 = v; i1 = e; }
                else if (v > b2) { b3 = b2; b2 = v; i2 = e; }
                else if (v > b3) { b3 = v; }
            }
        }
        const float g   = __expf(b2 - b1);
        const float inv = 1.0f / (1.0f + g);
        const size_t o  = (size_t)(row0 + r) * 2;
        out[o]     = (float)i1;
        out[o + 1] = (float)i2;
        out[65536 + o]     = inv;
        out[65536 + o + 1] = g * inv;
        flags[row0 + r] = ((b1 - b2 < DELTA) || (b2 - b3 < DELTA)) ? 1 : 0;
    }
}

// ---- pass2: fp64 repair of flagged rows (unchanged) ----
__global__ __launch_bounds__(256, 2)
void router_pass2(const float* __restrict__ x,
                  const float* __restrict__ w,
                  float* __restrict__ out,
                  const int* __restrict__ flags)
{
    const int wv   = threadIdx.x >> 6;
    const int lane = threadIdx.x & 63;
    const int base = blockIdx.x * 64 + wv * 16;

    for (int r = 0; r < 16; ++r) {
        const int row = base + r;
        if (!flags[row]) continue;   // wave-uniform

        const float* lg = out + 131072 + (size_t)row * 64;
        const float my = lg[lane];
        float wval = my;

        int ec[4];
#pragma unroll
        for (int m = 0; m < 4; ++m) {
            float v = wval;
            int   id = lane;
            for (int off = 32; off; off >>= 1) {
                const float ov = __shfl_xor(v, off);
                const int   oi = __shfl_xor(id, off);
                if (ov > v || (ov == v && oi < id)) { v = ov; id = oi; }
            }
            ec[m] = id;
            if (lane == id) wval = -3.4e38f;
        }

        double s0 = 0.0, s1 = 0.0, s2 = 0.0, s3 = 0.0;
        const float* xr = x + (size_t)row * 4096;
        const float* w0 = w + (size_t)ec[0] * 4096;
        const float* w1 = w + (size_t)ec[1] * 4096;
        const float* w2 = w + (size_t)ec[2] * 4096;
        const float* w3 = w + (size_t)ec[3] * 4096;
        for (int k = lane; k < 4096; k += 64) {
            const double xd = (double)xr[k];
            s0 += xd * (double)w0[k];
            s1 += xd * (double)w1[k];
            s2 += xd * (double)w2[k];
            s3 += xd * (double)w3[k];
        }
        for (int off = 32; off; off >>= 1) {
            s0 += __shfl_xor(s0, off);
            s1 += __shfl_xor(s1, off);
            s2 += __shfl_xor(s2, off);
            s3 += __shfl_xor(s3, off);
        }

        if (lane == 0) {
            double v4[4] = { s0, s1, s2, s3 };
            int    id[4] = { ec[0], ec[1], ec[2], ec[3] };
#pragma unroll
            for (int a = 0; a < 3; ++a)
#pragma unroll
                for (int b = a + 1; b < 4; ++b)
                    if (v4[b] > v4[a] || (v4[b] == v4[a] && id[b] < id[a])) {
                        double tv = v4[a]; v4[a] = v4[b]; v4[b] = tv;
                        int    ti = id[a]; id[a] = id[b]; id[b] = ti;
                    }
            const double g   = exp(v4[1] - v4[0]);
            const double inv = 1.0 / (1.0 + g);
            const size_t o   = (size_t)row * 2;
            out[o]     = (float)id[0];
            out[o + 1] = (float)id[1];
            out[65536 + o]     = (float)inv;
            out[65536 + o + 1] = (float)(g * inv);
        }
    }
}

extern "C" void kernel_launch(void* const* d_in, const int* in_sizes, int n_in,
                              void* d_out, int out_size, void* d_ws, size_t ws_size,
                              hipStream_t stream) {
    const float* x = (const float*)d_in[0];   // [8,4096,4096]
    const float* w = (const float*)d_in[1];   // [64,4096]
    float* out = (float*)d_out;
    int* flags = (int*)d_ws;                                        // 128 KB
    unsigned short* wsp = (unsigned short*)((char*)d_ws + 131072);  // 1 MB hi+lo

    hipLaunchKernelGGL(router_wconv, dim3(256), dim3(256), 0, stream, w, wsp);
    hipLaunchKernelGGL(router_pass1, dim3(512), dim3(256), 0, stream, x, wsp, out, flags);
    hipLaunchKernelGGL(router_pass2, dim3(512), dim3(256), 0, stream, x, w, out, flags);
}

// Round 3
// 860.741 us; speedup vs baseline: 1.3743x; 1.0159x over previous
//
#include <hip/hip_runtime.h>
#include <math.h>

// Router: logits = x[32768,4096] @ w[64,4096]^T, softmax->top2->renorm.
//
// MFMA version: fp32 inputs split into bf16 hi+lo (x=xh+xl, w=wh+wl, truncation),
// logits = xh*wh + xl*wh + xh*wl via mfma_f32_16x16x32_bf16 (error ~1e-5 << DELTA).
//
// v3: single fused kernel (wconv stays separate, tiny).
//   - K-loop identical to v2: barrier-free, global_load_lds (16B) double-buffered,
//     pre-swizzled global source + swizzled ds_read_b128, counted vmcnt(8),
//     in-register hi/lo split.
//   - fp64 repair of ambiguous rows (gap < DELTA) fused into the epilogue:
//     each block repairs its own <=64 rows using logits already in LDS.
//     No flags workspace, no second sweep kernel.
//
// d_out layout (float32):
//   [0      , 65536 ) : indices [8,4096,2] as float
//   [65536  , 131072) : weights [8,4096,2]
//   [131072 , end   ) : logits  [8,4096,64]
//
// d_ws layout:
//   [0, 1M): w split bf16: hi plane [64][4096] ushort, then lo plane

#define DELTA  1e-3f
#define LS     68            // logits LDS stride (floats)
#define WPLANE 262144        // elems per w bf16 plane (64*4096)
#define NT     32            // K tiles (4096 / 128)

typedef __bf16 bf16x8 __attribute__((ext_vector_type(8)));
typedef float  f32x4  __attribute__((ext_vector_type(4)));

#define MFMA(a, b, c) __builtin_amdgcn_mfma_f32_16x16x32_bf16(a, b, c, 0, 0, 0)

#define GLL16(gp, lp) __builtin_amdgcn_global_load_lds(                          \
    (const __attribute__((address_space(1))) unsigned*)(gp),                     \
    (__attribute__((address_space(3))) unsigned*)(lp), 16, 0, 0)

__device__ __forceinline__ void split1(float x, unsigned short& h, unsigned short& l)
{
    const unsigned xb = __float_as_uint(x);
    const unsigned hb = xb & 0xffff0000u;
    h = (unsigned short)(hb >> 16);
    const float fl = x - __uint_as_float(hb);      // exact in fp32
    l = (unsigned short)(__float_as_uint(fl) >> 16);
}

// 8 fp32 -> bf16 hi plane + bf16 lo plane (truncation; identical to split1)
__device__ __forceinline__ void split8(const f32x4 v0, const f32x4 v1,
                                       bf16x8& ah, bf16x8& al)
{
    union U { bf16x8 v; unsigned u[4]; };
    U h, l;
    const unsigned a0 = __float_as_uint(v0[0]), a1 = __float_as_uint(v0[1]);
    const unsigned a2 = __float_as_uint(v0[2]), a3 = __float_as_uint(v0[3]);
    const unsigned b0 = __float_as_uint(v1[0]), b1 = __float_as_uint(v1[1]);
    const unsigned b2 = __float_as_uint(v1[2]), b3 = __float_as_uint(v1[3]);
    h.u[0] = (a0 >> 16) | (a1 & 0xffff0000u);
    h.u[1] = (a2 >> 16) | (a3 & 0xffff0000u);
    h.u[2] = (b0 >> 16) | (b1 & 0xffff0000u);
    h.u[3] = (b2 >> 16) | (b3 & 0xffff0000u);
    const float f0 = v0[0] - __uint_as_float(a0 & 0xffff0000u);
    const float f1 = v0[1] - __uint_as_float(a1 & 0xffff0000u);
    const float f2 = v0[2] - __uint_as_float(a2 & 0xffff0000u);
    const float f3 = v0[3] - __uint_as_float(a3 & 0xffff0000u);
    const float f4 = v1[0] - __uint_as_float(b0 & 0xffff0000u);
    const float f5 = v1[1] - __uint_as_float(b1 & 0xffff0000u);
    const float f6 = v1[2] - __uint_as_float(b2 & 0xffff0000u);
    const float f7 = v1[3] - __uint_as_float(b3 & 0xffff0000u);
    l.u[0] = (__float_as_uint(f0) >> 16) | (__float_as_uint(f1) & 0xffff0000u);
    l.u[1] = (__float_as_uint(f2) >> 16) | (__float_as_uint(f3) & 0xffff0000u);
    l.u[2] = (__float_as_uint(f4) >> 16) | (__float_as_uint(f5) & 0xffff0000u);
    l.u[3] = (__float_as_uint(f6) >> 16) | (__float_as_uint(f7) & 0xffff0000u);
    ah = h.v;
    al = l.v;
}

// ---- w pre-split: fp32 [64][4096] -> bf16 hi/lo planes in workspace ----
__global__ __launch_bounds__(256)
void router_wconv(const float* __restrict__ w, unsigned short* __restrict__ wsp)
{
    const int i = (blockIdx.x * 256 + threadIdx.x) * 4;   // 256 blocks cover 262144
    const float4 v = *(const float4*)(w + i);
    ushort4 h4, l4;
    split1(v.x, h4.x, l4.x);
    split1(v.y, h4.y, l4.y);
    split1(v.z, h4.z, l4.z);
    split1(v.w, h4.w, l4.w);
    *(ushort4*)(wsp + i)          = h4;
    *(ushort4*)(wsp + WPLANE + i) = l4;
}

// ---- fused: MFMA GEMM + logits + top-2 + inline fp64 repair ----
// BM=64 rows/block, 256 threads (4 waves x 16 rows), KT=128, grid 512.
__global__ __launch_bounds__(256, 2)
void router_pass1(const float* __restrict__ x,
                  const unsigned short* __restrict__ wsp,
                  const float* __restrict__ w,
                  float* __restrict__ out)
{
    // two fp32 A-tile buffers [64 rows][512B]; epilogue overlays logits + flags
    __shared__ __align__(16) char smem[65536];

    const int tid  = threadIdx.x;
    const int lane = tid & 63;
    const int wv   = tid >> 6;                  // 0..3
    const int row0 = blockIdx.x * 64;

    const int fr = lane & 15;                   // frag row (A) / col (B,D)
    const int fq = lane >> 4;                   // 0..3; k offset = fq*8

    f32x4 acc[4];
#pragma unroll
    for (int ct = 0; ct < 4; ++ct) {
        acc[ct][0] = 0.f; acc[ct][1] = 0.f; acc[ct][2] = 0.f; acc[ct][3] = 0.f;
    }

    // ---- staging addresses (loop-invariant; only tile offset varies) ----
    // subtile s = wv*8+j covers rows 2s,2s+1 -> wave wv stages rows wv*16..+15,
    // exactly the rows it consumes (wave-private LDS, no barriers in K loop).
    const int half  = lane >> 5;                 // 0/1: which row of the subtile
    const unsigned colb = (unsigned)((lane & 31) * 16);
    const char* gsrc[8];
    char*       lbas[8];
#pragma unroll
    for (int j = 0; j < 8; ++j) {
        const int row = wv * 16 + 2 * j + half;
        const unsigned swz = colb ^ ((unsigned)(row & 7) << 4);  // pre-swizzled source
        gsrc[j] = (const char*)x + (size_t)(row0 + row) * 16384 + swz;
        lbas[j] = smem + (wv * 8 + j) * 1024;                    // linear LDS dest
    }

    // B fragment global bases: lane reads w[e=ct*16+fr][k0+fq*8 .. +7] (16B, L2)
    const unsigned short* wb[4];
#pragma unroll
    for (int ct = 0; ct < 4; ++ct)
        wb[ct] = wsp + (size_t)(ct * 16 + fr) * 4096 + fq * 8;

    // A fragment read base (swizzled ds_read_b128)
    const int arow = wv * 16 + fr;
    const unsigned aswz = (unsigned)((arow & 7) << 4);
    const char* abase = smem + arow * 512;

    // prologue: issue tile 0 into buf 0
#pragma unroll
    for (int j = 0; j < 8; ++j) GLL16(gsrc[j], lbas[j]);

#pragma unroll 1
    for (int t = 0; t < NT; ++t) {
        if (t + 1 < NT) {
            const size_t go = (size_t)(t + 1) * 512;
            const int    bo = ((t + 1) & 1) * 32768;
#pragma unroll
            for (int j = 0; j < 8; ++j) GLL16(gsrc[j] + go, lbas[j] + bo);
            // tile t's 8 loads complete; tile t+1's 8 stay in flight
            asm volatile("s_waitcnt vmcnt(8)" ::: "memory");
        } else {
            asm volatile("s_waitcnt vmcnt(0)" ::: "memory");
        }
        __builtin_amdgcn_sched_barrier(0);

        const char* bufc = abase + (t & 1) * 32768;
#pragma unroll
        for (int ks = 0; ks < 4; ++ks) {
            const unsigned i0 = (unsigned)(ks * 128 + fq * 32);
            const f32x4 v0 = *(const f32x4*)(bufc + ( i0        ^ aswz));
            const f32x4 v1 = *(const f32x4*)(bufc + ((i0 + 16u) ^ aswz));
            bf16x8 ah, al;
            split8(v0, v1, ah, al);
#pragma unroll
            for (int ct = 0; ct < 4; ++ct) {
                const unsigned short* p = wb[ct] + t * 128 + ks * 32;
                const bf16x8 bh = *(const bf16x8*)(p);
                const bf16x8 bl = *(const bf16x8*)(p + WPLANE);
                acc[ct] = MFMA(ah, bh, acc[ct]);
                acc[ct] = MFMA(al, bh, acc[ct]);
                acc[ct] = MFMA(ah, bl, acc[ct]);
            }
        }
    }

    // ---- epilogue: logits via LDS (overlay A buffers), top-2, flags ----
    __syncthreads();                            // all waves done with A buffers
    float* l_lds   = (float*)smem;              // [64][LS] = 17408 B
    int*   flg_lds = (int*)(smem + 32768);      // 64 ints (disjoint from l_lds)

    // D layout: col = lane&15, row = (lane>>4)*4 + reg  [m89-verified]
#pragma unroll
    for (int ct = 0; ct < 4; ++ct) {
#pragma unroll
        for (int i = 0; i < 4; ++i) {
            l_lds[(wv * 16 + fq * 4 + i) * LS + ct * 16 + fr] = acc[ct][i];
        }
    }
    __syncthreads();

    {
        float* lg = out + 131072 + (size_t)row0 * 64;
#pragma unroll
        for (int j = 0; j < 4; ++j) {
            const int f = j * 1024 + tid * 4;
            const int r = f >> 6, e = f & 63;
            const float4 v = *(const float4*)(&l_lds[r * LS + e]);
            *(float4*)(lg + f) = v;
        }
    }

    if (tid < 64) {
        const int r = tid;
        float b1 = -3.4e38f, b2 = -3.4e38f, b3 = -3.4e38f;
        int i1 = 0, i2 = 0;
        for (int eq = 0; eq < 16; ++eq) {
            const float4 v4 = *(const float4*)(&l_lds[r * LS + eq * 4]);
            const float vv[4] = {v4.x, v4.y, v4.z, v4.w};
#pragma unroll
            for (int j = 0; j < 4; ++j) {
                const float v = vv[j];
                const int   e = eq * 4 + j;
                if (v > b1)      { b3 = b2; b2 = b1; i2 = i1; b1 = v; i1 = e; }
                else if (v > b2) { b3 = b2; b2 = v; i2 = e; }
                else if (v > b3) { b3 = v; }
            }
        }
        const int amb = ((b1 - b2 < DELTA) || (b2 - b3 < DELTA)) ? 1 : 0;
        flg_lds[r] = amb;
        if (!amb) {                 // unambiguous rows finalized here
            const float g   = __expf(b2 - b1);
            const float inv = 1.0f / (1.0f + g);
            const size_t o  = (size_t)(row0 + r) * 2;
            out[o]     = (float)i1;
            out[o + 1] = (float)i2;
            out[65536 + o]     = inv;
            out[65536 + o + 1] = g * inv;
        }
    }
    __syncthreads();

    // ---- inline fp64 repair: wave wv owns rows wv*16 .. wv*16+15 ----
    for (int i = 0; i < 16; ++i) {
        const int r = wv * 16 + i;
        if (!flg_lds[r]) continue;              // wave-uniform (LDS broadcast)
        const int row = row0 + r;

        float wval = l_lds[r * LS + lane];      // lane = expert, stride-4B: no conflicts

        int ec[4];
#pragma unroll
        for (int m = 0; m < 4; ++m) {
            float v = wval;
            int   id = lane;
            // argmax with lowest-index tie-break
            for (int off = 32; off; off >>= 1) {
                const float ov = __shfl_xor(v, off);
                const int   oi = __shfl_xor(id, off);
                if (ov > v || (ov == v && oi < id)) { v = ov; id = oi; }
            }
            ec[m] = id;                         // uniform across lanes
            if (lane == id) wval = -3.4e38f;
        }

        double s0 = 0.0, s1 = 0.0, s2 = 0.0, s3 = 0.0;
        const float* xr = x + (size_t)row * 4096;
        const float* w0 = w + (size_t)ec[0] * 4096;
        const float* w1 = w + (size_t)ec[1] * 4096;
        const float* w2 = w + (size_t)ec[2] * 4096;
        const float* w3 = w + (size_t)ec[3] * 4096;
        for (int k = lane; k < 4096; k += 64) {
            const double xd = (double)xr[k];
            s0 += xd * (double)w0[k];
            s1 += xd * (double)w1[k];
            s2 += xd * (double)w2[k];
            s3 += xd * (double)w3[k];
        }
        for (int off = 32; off; off >>= 1) {
            s0 += __shfl_xor(s0, off);
            s1 += __shfl_xor(s1, off);
            s2 += __shfl_xor(s2, off);
            s3 += __shfl_xor(s3, off);
        }

        if (lane == 0) {
            double v4[4] = { s0, s1, s2, s3 };
            int    id[4] = { ec[0], ec[1], ec[2], ec[3] };
#pragma unroll
            for (int a = 0; a < 3; ++a)
#pragma unroll
                for (int b = a + 1; b < 4; ++b)
                    if (v4[b] > v4[a] || (v4[b] == v4[a] && id[b] < id[a])) {
                        double tv = v4[a]; v4[a] = v4[b]; v4[b] = tv;
                        int    ti = id[a]; id[a] = id[b]; id[b] = ti;
                    }
            const double g   = exp(v4[1] - v4[0]);
            const double inv = 1.0 / (1.0 + g);
            const size_t o   = (size_t)row * 2;
            out[o]     = (float)id[0];
            out[o + 1] = (float)id[1];
            out[65536 + o]     = (float)inv;
            out[65536 + o + 1] = (float)(g * inv);
        }
    }
}

extern "C" void kernel_launch(void* const* d_in, const int* in_sizes, int n_in,
                              void* d_out, int out_size, void* d_ws, size_t ws_size,
                              hipStream_t stream) {
    const float* x = (const float*)d_in[0];   // [8,4096,4096]
    const float* w = (const float*)d_in[1];   // [64,4096]
    float* out = (float*)d_out;
    unsigned short* wsp = (unsigned short*)d_ws;   // 1 MB: w bf16 hi+lo planes

    hipLaunchKernelGGL(router_wconv, dim3(256), dim3(256), 0, stream, w, wsp);
    hipLaunchKernelGGL(router_pass1, dim3(512), dim3(256), 0, stream, x, wsp, w, out);
}

// Round 4
// 848.348 us; speedup vs baseline: 1.3943x; 1.0146x over previous
//
#include <hip/hip_runtime.h>
#include <math.h>

// Router: logits = x[32768,4096] @ w[64,4096]^T, softmax->top2->renorm.
//
// MFMA version: fp32 inputs split into bf16 hi+lo (x=xh+xl, w=wh+wl, truncation),
// logits = xh*wh + xl*wh + xh*wl via mfma_f32_16x16x32_bf16 (error ~1e-5 << DELTA).
//
// v4: per-wave K-phase stagger.
//   All waves previously marched through the same 512B column window of x in
//   lockstep (rows strided 16KB) -> address bits [9:13] identical machine-wide
//   -> HBM channel congestion (measured 832 GB/s, 10% peak). Wave g now starts
//   its K loop at tile t0 = g & 31 and wraps, spreading traffic over all 32
//   column windows at every instant. K-loop body unchanged from v3:
//   barrier-free, wave-private LDS, global_load_lds (16B) double-buffered,
//   pre-swizzled global source + swizzled ds_read_b128, counted vmcnt(8),
//   in-register hi/lo split. Inline fp64 repair of ambiguous rows.
//
// d_out layout (float32):
//   [0      , 65536 ) : indices [8,4096,2] as float
//   [65536  , 131072) : weights [8,4096,2]
//   [131072 , end   ) : logits  [8,4096,64]
//
// d_ws layout:
//   [0, 1M): w split bf16: hi plane [64][4096] ushort, then lo plane

#define DELTA  1e-3f
#define LS     68            // logits LDS stride (floats)
#define WPLANE 262144        // elems per w bf16 plane (64*4096)
#define NT     32            // K tiles (4096 / 128)

typedef __bf16 bf16x8 __attribute__((ext_vector_type(8)));
typedef float  f32x4  __attribute__((ext_vector_type(4)));

#define MFMA(a, b, c) __builtin_amdgcn_mfma_f32_16x16x32_bf16(a, b, c, 0, 0, 0)

#define GLL16(gp, lp) __builtin_amdgcn_global_load_lds(                          \
    (const __attribute__((address_space(1))) unsigned*)(gp),                     \
    (__attribute__((address_space(3))) unsigned*)(lp), 16, 0, 0)

__device__ __forceinline__ void split1(float x, unsigned short& h, unsigned short& l)
{
    const unsigned xb = __float_as_uint(x);
    const unsigned hb = xb & 0xffff0000u;
    h = (unsigned short)(hb >> 16);
    const float fl = x - __uint_as_float(hb);      // exact in fp32
    l = (unsigned short)(__float_as_uint(fl) >> 16);
}

// 8 fp32 -> bf16 hi plane + bf16 lo plane (truncation; identical to split1)
__device__ __forceinline__ void split8(const f32x4 v0, const f32x4 v1,
                                       bf16x8& ah, bf16x8& al)
{
    union U { bf16x8 v; unsigned u[4]; };
    U h, l;
    const unsigned a0 = __float_as_uint(v0[0]), a1 = __float_as_uint(v0[1]);
    const unsigned a2 = __float_as_uint(v0[2]), a3 = __float_as_uint(v0[3]);
    const unsigned b0 = __float_as_uint(v1[0]), b1 = __float_as_uint(v1[1]);
    const unsigned b2 = __float_as_uint(v1[2]), b3 = __float_as_uint(v1[3]);
    h.u[0] = (a0 >> 16) | (a1 & 0xffff0000u);
    h.u[1] = (a2 >> 16) | (a3 & 0xffff0000u);
    h.u[2] = (b0 >> 16) | (b1 & 0xffff0000u);
    h.u[3] = (b2 >> 16) | (b3 & 0xffff0000u);
    const float f0 = v0[0] - __uint_as_float(a0 & 0xffff0000u);
    const float f1 = v0[1] - __uint_as_float(a1 & 0xffff0000u);
    const float f2 = v0[2] - __uint_as_float(a2 & 0xffff0000u);
    const float f3 = v0[3] - __uint_as_float(a3 & 0xffff0000u);
    const float f4 = v1[0] - __uint_as_float(b0 & 0xffff0000u);
    const float f5 = v1[1] - __uint_as_float(b1 & 0xffff0000u);
    const float f6 = v1[2] - __uint_as_float(b2 & 0xffff0000u);
    const float f7 = v1[3] - __uint_as_float(b3 & 0xffff0000u);
    l.u[0] = (__float_as_uint(f0) >> 16) | (__float_as_uint(f1) & 0xffff0000u);
    l.u[1] = (__float_as_uint(f2) >> 16) | (__float_as_uint(f3) & 0xffff0000u);
    l.u[2] = (__float_as_uint(f4) >> 16) | (__float_as_uint(f5) & 0xffff0000u);
    l.u[3] = (__float_as_uint(f6) >> 16) | (__float_as_uint(f7) & 0xffff0000u);
    ah = h.v;
    al = l.v;
}

// ---- w pre-split: fp32 [64][4096] -> bf16 hi/lo planes in workspace ----
__global__ __launch_bounds__(256)
void router_wconv(const float* __restrict__ w, unsigned short* __restrict__ wsp)
{
    const int i = (blockIdx.x * 256 + threadIdx.x) * 4;   // 256 blocks cover 262144
    const float4 v = *(const float4*)(w + i);
    ushort4 h4, l4;
    split1(v.x, h4.x, l4.x);
    split1(v.y, h4.y, l4.y);
    split1(v.z, h4.z, l4.z);
    split1(v.w, h4.w, l4.w);
    *(ushort4*)(wsp + i)          = h4;
    *(ushort4*)(wsp + WPLANE + i) = l4;
}

// ---- fused: MFMA GEMM + logits + top-2 + inline fp64 repair ----
// BM=64 rows/block, 256 threads (4 waves x 16 rows), KT=128, grid 512.
__global__ __launch_bounds__(256, 2)
void router_pass1(const float* __restrict__ x,
                  const unsigned short* __restrict__ wsp,
                  const float* __restrict__ w,
                  float* __restrict__ out)
{
    // two fp32 A-tile buffers [64 rows][512B]; epilogue overlays logits + flags
    __shared__ __align__(16) char smem[65536];

    const int tid  = threadIdx.x;
    const int lane = tid & 63;
    const int wv   = tid >> 6;                  // 0..3
    const int row0 = blockIdx.x * 64;

    const int fr = lane & 15;                   // frag row (A) / col (B,D)
    const int fq = lane >> 4;                   // 0..3; k offset = fq*8

    // per-wave K-phase: 2048 waves spread evenly over the 32 column windows
    const int t0 = ((blockIdx.x << 2) + wv) & 31;

    f32x4 acc[4];
#pragma unroll
    for (int ct = 0; ct < 4; ++ct) {
        acc[ct][0] = 0.f; acc[ct][1] = 0.f; acc[ct][2] = 0.f; acc[ct][3] = 0.f;
    }

    // ---- staging addresses (loop-invariant; only tile offset varies) ----
    // subtile s = wv*8+j covers rows 2s,2s+1 -> wave wv stages rows wv*16..+15,
    // exactly the rows it consumes (wave-private LDS, no barriers in K loop).
    const int half  = lane >> 5;                 // 0/1: which row of the subtile
    const unsigned colb = (unsigned)((lane & 31) * 16);
    const char* gsrc[8];
    char*       lbas[8];
#pragma unroll
    for (int j = 0; j < 8; ++j) {
        const int row = wv * 16 + 2 * j + half;
        const unsigned swz = colb ^ ((unsigned)(row & 7) << 4);  // pre-swizzled source
        gsrc[j] = (const char*)x + (size_t)(row0 + row) * 16384 + swz;
        lbas[j] = smem + (wv * 8 + j) * 1024;                    // linear LDS dest
    }

    // B fragment global bases: lane reads w[e=ct*16+fr][k0+fq*8 .. +7] (16B, L2)
    const unsigned short* wb[4];
#pragma unroll
    for (int ct = 0; ct < 4; ++ct)
        wb[ct] = wsp + (size_t)(ct * 16 + fr) * 4096 + fq * 8;

    // A fragment read base (swizzled ds_read_b128)
    const int arow = wv * 16 + fr;
    const unsigned aswz = (unsigned)((arow & 7) << 4);
    const char* abase = smem + arow * 512;

    // prologue: issue tile t0 into buf 0
#pragma unroll
    for (int j = 0; j < 8; ++j) GLL16(gsrc[j] + (size_t)t0 * 512, lbas[j]);

#pragma unroll 1
    for (int i = 0; i < NT; ++i) {
        const int t = (t0 + i) & 31;
        if (i + 1 < NT) {
            const int    tn = (t0 + i + 1) & 31;
            const size_t go = (size_t)tn * 512;
            const int    bo = ((i + 1) & 1) * 32768;
#pragma unroll
            for (int j = 0; j < 8; ++j) GLL16(gsrc[j] + go, lbas[j] + bo);
            // tile i's 8 loads complete; tile i+1's 8 stay in flight
            asm volatile("s_waitcnt vmcnt(8)" ::: "memory");
        } else {
            asm volatile("s_waitcnt vmcnt(0)" ::: "memory");
        }
        __builtin_amdgcn_sched_barrier(0);

        const char* bufc = abase + (i & 1) * 32768;
#pragma unroll
        for (int ks = 0; ks < 4; ++ks) {
            const unsigned i0 = (unsigned)(ks * 128 + fq * 32);
            const f32x4 v0 = *(const f32x4*)(bufc + ( i0        ^ aswz));
            const f32x4 v1 = *(const f32x4*)(bufc + ((i0 + 16u) ^ aswz));
            bf16x8 ah, al;
            split8(v0, v1, ah, al);
#pragma unroll
            for (int ct = 0; ct < 4; ++ct) {
                const unsigned short* p = wb[ct] + t * 128 + ks * 32;
                const bf16x8 bh = *(const bf16x8*)(p);
                const bf16x8 bl = *(const bf16x8*)(p + WPLANE);
                acc[ct] = MFMA(ah, bh, acc[ct]);
                acc[ct] = MFMA(al, bh, acc[ct]);
                acc[ct] = MFMA(ah, bl, acc[ct]);
            }
        }
    }

    // ---- epilogue: logits via LDS (overlay A buffers), top-2, flags ----
    __syncthreads();                            // all waves done with A buffers
    float* l_lds   = (float*)smem;              // [64][LS] = 17408 B
    int*   flg_lds = (int*)(smem + 32768);      // 64 ints (disjoint from l_lds)

    // D layout: col = lane&15, row = (lane>>4)*4 + reg  [m89-verified]
#pragma unroll
    for (int ct = 0; ct < 4; ++ct) {
#pragma unroll
        for (int i = 0; i < 4; ++i) {
            l_lds[(wv * 16 + fq * 4 + i) * LS + ct * 16 + fr] = acc[ct][i];
        }
    }
    __syncthreads();

    {
        float* lg = out + 131072 + (size_t)row0 * 64;
#pragma unroll
        for (int j = 0; j < 4; ++j) {
            const int f = j * 1024 + tid * 4;
            const int r = f >> 6, e = f & 63;
            const float4 v = *(const float4*)(&l_lds[r * LS + e]);
            *(float4*)(lg + f) = v;
        }
    }

    if (tid < 64) {
        const int r = tid;
        float b1 = -3.4e38f, b2 = -3.4e38f, b3 = -3.4e38f;
        int i1 = 0, i2 = 0;
        for (int eq = 0; eq < 16; ++eq) {
            const float4 v4 = *(const float4*)(&l_lds[r * LS + eq * 4]);
            const float vv[4] = {v4.x, v4.y, v4.z, v4.w};
#pragma unroll
            for (int j = 0; j < 4; ++j) {
                const float v = vv[j];
                const int   e = eq * 4 + j;
                if (v > b1)      { b3 = b2; b2 = b1; i2 = i1; b1 = v; i1 = e; }
                else if (v > b2) { b3 = b2; b2 = v; i2 = e; }
                else if (v > b3) { b3 = v; }
            }
        }
        const int amb = ((b1 - b2 < DELTA) || (b2 - b3 < DELTA)) ? 1 : 0;
        flg_lds[r] = amb;
        if (!amb) {                 // unambiguous rows finalized here
            const float g   = __expf(b2 - b1);
            const float inv = 1.0f / (1.0f + g);
            const size_t o  = (size_t)(row0 + r) * 2;
            out[o]     = (float)i1;
            out[o + 1] = (float)i2;
            out[65536 + o]     = inv;
            out[65536 + o + 1] = g * inv;
        }
    }
    __syncthreads();

    // ---- inline fp64 repair: wave wv owns rows wv*16 .. wv*16+15 ----
    for (int i = 0; i < 16; ++i) {
        const int r = wv * 16 + i;
        if (!flg_lds[r]) continue;              // wave-uniform (LDS broadcast)
        const int row = row0 + r;

        float wval = l_lds[r * LS + lane];      // lane = expert, stride-4B: no conflicts

        int ec[4];
#pragma unroll
        for (int m = 0; m < 4; ++m) {
            float v = wval;
            int   id = lane;
            // argmax with lowest-index tie-break
            for (int off = 32; off; off >>= 1) {
                const float ov = __shfl_xor(v, off);
                const int   oi = __shfl_xor(id, off);
                if (ov > v || (ov == v && oi < id)) { v = ov; id = oi; }
            }
            ec[m] = id;                         // uniform across lanes
            if (lane == id) wval = -3.4e38f;
        }

        double s0 = 0.0, s1 = 0.0, s2 = 0.0, s3 = 0.0;
        const float* xr = x + (size_t)row * 4096;
        const float* w0 = w + (size_t)ec[0] * 4096;
        const float* w1 = w + (size_t)ec[1] * 4096;
        const float* w2 = w + (size_t)ec[2] * 4096;
        const float* w3 = w + (size_t)ec[3] * 4096;
        for (int k = lane; k < 4096; k += 64) {
            const double xd = (double)xr[k];
            s0 += xd * (double)w0[k];
            s1 += xd * (double)w1[k];
            s2 += xd * (double)w2[k];
            s3 += xd * (double)w3[k];
        }
        for (int off = 32; off; off >>= 1) {
            s0 += __shfl_xor(s0, off);
            s1 += __shfl_xor(s1, off);
            s2 += __shfl_xor(s2, off);
            s3 += __shfl_xor(s3, off);
        }

        if (lane == 0) {
            double v4[4] = { s0, s1, s2, s3 };
            int    id[4] = { ec[0], ec[1], ec[2], ec[3] };
#pragma unroll
            for (int a = 0; a < 3; ++a)
#pragma unroll
                for (int b = a + 1; b < 4; ++b)
                    if (v4[b] > v4[a] || (v4[b] == v4[a] && id[b] < id[a])) {
                        double tv = v4[a]; v4[a] = v4[b]; v4[b] = tv;
                        int    ti = id[a]; id[a] = id[b]; id[b] = ti;
                    }
            const double g   = exp(v4[1] - v4[0]);
            const double inv = 1.0 / (1.0 + g);
            const size_t o   = (size_t)row * 2;
            out[o]     = (float)id[0];
            out[o + 1] = (float)id[1];
            out[65536 + o]     = (float)inv;
            out[65536 + o + 1] = (float)(g * inv);
        }
    }
}

extern "C" void kernel_launch(void* const* d_in, const int* in_sizes, int n_in,
                              void* d_out, int out_size, void* d_ws, size_t ws_size,
                              hipStream_t stream) {
    const float* x = (const float*)d_in[0];   // [8,4096,4096]
    const float* w = (const float*)d_in[1];   // [64,4096]
    float* out = (float*)d_out;
    unsigned short* wsp = (unsigned short*)d_ws;   // 1 MB: w bf16 hi+lo planes

    hipLaunchKernelGGL(router_wconv, dim3(256), dim3(256), 0, stream, w, wsp);
    hipLaunchKernelGGL(router_pass1, dim3(512), dim3(256), 0, stream, x, wsp, w, out);
}